// Round 1
// baseline (171.292 us; speedup 1.0000x reference)
//
#include <hip/hip_runtime.h>
#include <hip/hip_bf16.h>
#include <math.h>

// Problem constants (from reference): B=32, T=2048, H=512, D=2H=1024
constexpr int B = 32;
constexpr int T = 2048;
constexpr int H = 512;
constexpr int D = 2 * H;     // 1024
constexpr int TS1 = 32;      // T-split for hsum kernel
constexpr int TS4 = 32;      // T-split for r kernel

// ---------------------------------------------------------------------------
// Kernel 1: hsum[b,d] = sum_t h[b,t,d] * mask[b,t,d & (H-1)]
// grid = B*TS1 blocks, 256 threads; each thread owns 4 consecutive d (float4).
// ---------------------------------------------------------------------------
__global__ void k_hsum(const float* __restrict__ h,
                       const float* __restrict__ mask,
                       float* __restrict__ hsum) {
    const int b   = blockIdx.x / TS1;
    const int ts  = blockIdx.x % TS1;
    const int tid = threadIdx.x;            // 0..255
    const int d4  = tid * 4;                // 0..1020
    const int md4 = d4 & (H - 1);           // mask tiled: d mod H (H=512 pow2)

    constexpr int TCH = T / TS1;            // 64 t-steps per block
    const int t0 = ts * TCH;

    const float4* hp = reinterpret_cast<const float4*>(
        h + (size_t)b * T * D + (size_t)t0 * D) + tid;
    const float4* mp = reinterpret_cast<const float4*>(
        mask + (size_t)b * T * H + (size_t)t0 * H) + (md4 >> 2);

    float4 acc = make_float4(0.f, 0.f, 0.f, 0.f);
    for (int t = 0; t < TCH; ++t) {
        float4 hv = hp[(size_t)t * (D / 4)];
        float4 mv = mp[(size_t)t * (H / 4)];
        acc.x += hv.x * mv.x;
        acc.y += hv.y * mv.y;
        acc.z += hv.z * mv.z;
        acc.w += hv.w * mv.w;
    }
    float* dst = hsum + b * D + d4;
    atomicAdd(dst + 0, acc.x);
    atomicAdd(dst + 1, acc.y);
    atomicAdd(dst + 2, acc.z);
    atomicAdd(dst + 3, acc.w);
}

// ---------------------------------------------------------------------------
// Kernel 2: beta[b,t] = dot(lstm[b,t,:], hsum[b,:])   (one wave per row)
// grid = B*T/4 blocks of 256 threads (4 waves/block).
// ---------------------------------------------------------------------------
__global__ void k_beta(const float* __restrict__ lstm,
                       const float* __restrict__ hsum,
                       float* __restrict__ beta) {
    const int wid  = blockIdx.x * 4 + (threadIdx.x >> 6);  // global row id
    const int lane = threadIdx.x & 63;
    const int b = wid >> 11;          // / T
    const int t = wid & (T - 1);      // % T

    const float4* lp = reinterpret_cast<const float4*>(
        lstm + (size_t)b * T * D + (size_t)t * D);
    const float4* hp = reinterpret_cast<const float4*>(hsum + b * D);

    float acc = 0.f;
#pragma unroll
    for (int k = 0; k < 4; ++k) {
        float4 lv = lp[lane + 64 * k];
        float4 hv = hp[lane + 64 * k];
        acc += lv.x * hv.x + lv.y * hv.y + lv.z * hv.z + lv.w * hv.w;
    }
#pragma unroll
    for (int off = 32; off >= 1; off >>= 1)
        acc += __shfl_xor(acc, off, 64);
    if (lane == 0) beta[wid] = acc;
}

// ---------------------------------------------------------------------------
// Kernel 3: alpha[b,:] = softmax(beta[b,:])  — one block per b, 256 threads,
// 8 elements per thread.
// ---------------------------------------------------------------------------
__global__ void k_softmax(const float* __restrict__ beta,
                          float* __restrict__ alpha) {
    const int b = blockIdx.x;
    const int tid = threadIdx.x;
    const float* bp = beta + b * T;

    float v[8];
    float m = -INFINITY;
#pragma unroll
    for (int i = 0; i < 8; ++i) {
        v[i] = bp[tid + i * 256];
        m = fmaxf(m, v[i]);
    }
#pragma unroll
    for (int o = 32; o >= 1; o >>= 1) m = fmaxf(m, __shfl_xor(m, o, 64));

    __shared__ float sm[4];
    __shared__ float ss[4];
    if ((tid & 63) == 0) sm[tid >> 6] = m;
    __syncthreads();
    m = fmaxf(fmaxf(sm[0], sm[1]), fmaxf(sm[2], sm[3]));

    float s = 0.f;
#pragma unroll
    for (int i = 0; i < 8; ++i) {
        v[i] = expf(v[i] - m);
        s += v[i];
    }
#pragma unroll
    for (int o = 32; o >= 1; o >>= 1) s += __shfl_xor(s, o, 64);
    if ((tid & 63) == 0) ss[tid >> 6] = s;
    __syncthreads();
    s = ss[0] + ss[1] + ss[2] + ss[3];

    const float inv = 1.f / s;
    float* ap = alpha + b * T;
#pragma unroll
    for (int i = 0; i < 8; ++i) ap[tid + i * 256] = v[i] * inv;
}

// ---------------------------------------------------------------------------
// Kernel 4: r[b,d] = sum_t alpha[b,t] * lstm[b,t,d]
// grid = B*TS4 blocks, 256 threads, float4 per thread, atomic accumulate.
// ---------------------------------------------------------------------------
__global__ void k_r(const float* __restrict__ lstm,
                    const float* __restrict__ alpha,
                    float* __restrict__ r) {
    const int b   = blockIdx.x / TS4;
    const int ts  = blockIdx.x % TS4;
    const int tid = threadIdx.x;

    constexpr int TCH = T / TS4;
    const int t0 = ts * TCH;

    const float4* lp = reinterpret_cast<const float4*>(
        lstm + (size_t)b * T * D + (size_t)t0 * D) + tid;
    const float* ap = alpha + b * T + t0;

    float4 acc = make_float4(0.f, 0.f, 0.f, 0.f);
    for (int t = 0; t < TCH; ++t) {
        float a = ap[t];
        float4 lv = lp[(size_t)t * (D / 4)];
        acc.x += a * lv.x;
        acc.y += a * lv.y;
        acc.z += a * lv.z;
        acc.w += a * lv.w;
    }
    float* dst = r + b * D + tid * 4;
    atomicAdd(dst + 0, acc.x);
    atomicAdd(dst + 1, acc.y);
    atomicAdd(dst + 2, acc.z);
    atomicAdd(dst + 3, acc.w);
}

// ---------------------------------------------------------------------------
extern "C" void kernel_launch(void* const* d_in, const int* in_sizes, int n_in,
                              void* d_out, int out_size, void* d_ws, size_t ws_size,
                              hipStream_t stream) {
    const float* h    = (const float*)d_in[0];   // [B,T,D]
    const float* lstm = (const float*)d_in[1];   // [B,T,D]
    const float* mask = (const float*)d_in[2];   // [B,T,H]

    float* out   = (float*)d_out;
    float* r     = out;            // [B,1,D] -> B*D floats
    float* alpha = out + B * D;    // [B,T]   -> B*T floats

    float* hsum = (float*)d_ws;        // B*D floats
    float* beta = hsum + B * D;        // B*T floats

    hipMemsetAsync(hsum, 0, (size_t)B * D * sizeof(float), stream);
    hipMemsetAsync(r,    0, (size_t)B * D * sizeof(float), stream);

    k_hsum   <<<B * TS1,     256, 0, stream>>>(h, mask, hsum);
    k_beta   <<<B * T / 4,   256, 0, stream>>>(lstm, hsum, beta);
    k_softmax<<<B,           256, 0, stream>>>(beta, alpha);
    k_r      <<<B * TS4,     256, 0, stream>>>(lstm, alpha, r);
}

// Round 2
// 150.996 us; speedup vs baseline: 1.1344x; 1.1344x over previous
//
#include <hip/hip_runtime.h>
#include <hip/hip_bf16.h>
#include <math.h>

// Problem constants (from reference): B=32, T=2048, H=512, D=2H=1024
constexpr int B = 32;
constexpr int T = 2048;
constexpr int H = 512;
constexpr int D = 2 * H;       // 1024
constexpr int TS1 = 32;        // T-split for hsum kernel
constexpr int NCH = 32;        // T-chunks per batch for fused kernel
constexpr int WPB = 4;         // waves per block
constexpr int NP  = NCH * WPB; // 128 online-softmax partials per batch
constexpr int RPW = T / NCH / WPB; // 16 rows per wave

// ---------------------------------------------------------------------------
// Kernel 0: zero hsum (avoid rocclr fillBuffer; deterministic, capture-safe)
// ---------------------------------------------------------------------------
__global__ void k_zero(float* __restrict__ p) {
    ((float4*)p)[blockIdx.x * 256 + threadIdx.x] =
        make_float4(0.f, 0.f, 0.f, 0.f);
}

// ---------------------------------------------------------------------------
// Kernel 1: hsum[b,d] = sum_t h[b,t,d] * mask[b,t,d & (H-1)]
// grid = B*TS1 blocks, 256 threads; each thread owns 4 consecutive d (float4).
// ---------------------------------------------------------------------------
__global__ void k_hsum(const float* __restrict__ h,
                       const float* __restrict__ mask,
                       float* __restrict__ hsum) {
    const int b   = blockIdx.x / TS1;
    const int ts  = blockIdx.x % TS1;
    const int tid = threadIdx.x;            // 0..255
    const int d4  = tid * 4;                // 0..1020
    const int md4 = d4 & (H - 1);           // mask tiled: d mod H

    constexpr int TCH = T / TS1;            // 64 t-steps per block
    const int t0 = ts * TCH;

    const float4* hp = reinterpret_cast<const float4*>(
        h + (size_t)b * T * D + (size_t)t0 * D) + tid;
    const float4* mp = reinterpret_cast<const float4*>(
        mask + (size_t)b * T * H + (size_t)t0 * H) + (md4 >> 2);

    float4 acc = make_float4(0.f, 0.f, 0.f, 0.f);
    for (int t = 0; t < TCH; ++t) {
        float4 hv = hp[(size_t)t * (D / 4)];
        float4 mv = mp[(size_t)t * (H / 4)];
        acc.x += hv.x * mv.x;
        acc.y += hv.y * mv.y;
        acc.z += hv.z * mv.z;
        acc.w += hv.w * mv.w;
    }
    float* dst = hsum + b * D + d4;
    atomicAdd(dst + 0, acc.x);
    atomicAdd(dst + 1, acc.y);
    atomicAdd(dst + 2, acc.z);
    atomicAdd(dst + 3, acc.w);
}

// ---------------------------------------------------------------------------
// Kernel 2 (fused): single pass over lstm.
// Per wave: for its 16 rows t, compute beta[b,t] = lstm[b,t,:].hsum[b,:]
// (butterfly-reduced -> wave-uniform), then online-softmax accumulate
// racc[D] (16 floats/lane), tracking running (m, s). Writes one partial
// (m, s, racc[1024]) per wave.  lstm is read exactly ONCE.
// ---------------------------------------------------------------------------
__global__ void k_fused(const float* __restrict__ lstm,
                        const float* __restrict__ hsum,
                        float* __restrict__ beta,
                        float* __restrict__ pm,
                        float* __restrict__ ps,
                        float* __restrict__ pr) {
    const int b    = blockIdx.x / NCH;
    const int ch   = blockIdx.x % NCH;
    const int w    = threadIdx.x >> 6;
    const int lane = threadIdx.x & 63;
    const int pidx = ch * WPB + w;

    // hsum fragment for this lane's 16 columns (cols (lane+64k)*4 .. +3)
    const float4* hp = reinterpret_cast<const float4*>(hsum + (size_t)b * D);
    float4 hv[4];
#pragma unroll
    for (int k = 0; k < 4; ++k) hv[k] = hp[lane + 64 * k];

    float m = -INFINITY, s = 0.f;
    float4 racc[4];
#pragma unroll
    for (int k = 0; k < 4; ++k) racc[k] = make_float4(0.f, 0.f, 0.f, 0.f);

    const int t0 = ch * (T / NCH);   // 64 rows per block
    for (int i = 0; i < RPW; ++i) {
        const int t = t0 + i * WPB + w;
        const float4* lp = reinterpret_cast<const float4*>(
            lstm + ((size_t)b * T + t) * D);
        float4 lv[4];
#pragma unroll
        for (int k = 0; k < 4; ++k) lv[k] = lp[lane + 64 * k];

        float acc = 0.f;
#pragma unroll
        for (int k = 0; k < 4; ++k) {
            acc += lv[k].x * hv[k].x + lv[k].y * hv[k].y +
                   lv[k].z * hv[k].z + lv[k].w * hv[k].w;
        }
#pragma unroll
        for (int o = 32; o >= 1; o >>= 1) acc += __shfl_xor(acc, o, 64);
        if (lane == 0) beta[b * T + t] = acc;

        // online softmax update (branch is wave-uniform: acc is reduced)
        if (acc <= m) {
            const float e = expf(acc - m);
            s += e;
#pragma unroll
            for (int k = 0; k < 4; ++k) {
                racc[k].x = fmaf(e, lv[k].x, racc[k].x);
                racc[k].y = fmaf(e, lv[k].y, racc[k].y);
                racc[k].z = fmaf(e, lv[k].z, racc[k].z);
                racc[k].w = fmaf(e, lv[k].w, racc[k].w);
            }
        } else {
            const float c = expf(m - acc);   // expf(-inf)=0 handles first row
            s = fmaf(s, c, 1.f);
#pragma unroll
            for (int k = 0; k < 4; ++k) {
                racc[k].x = fmaf(racc[k].x, c, lv[k].x);
                racc[k].y = fmaf(racc[k].y, c, lv[k].y);
                racc[k].z = fmaf(racc[k].z, c, lv[k].z);
                racc[k].w = fmaf(racc[k].w, c, lv[k].w);
            }
            m = acc;
        }
    }

    if (lane == 0) {
        pm[b * NP + pidx] = m;
        ps[b * NP + pidx] = s;
    }
    float4* prp = reinterpret_cast<float4*>(
        pr + ((size_t)(b * NP + pidx)) * D);
#pragma unroll
    for (int k = 0; k < 4; ++k) prp[lane + 64 * k] = racc[k];
}

// ---------------------------------------------------------------------------
// Kernel 3: combine partials -> r[b,:] and alpha[b,:]. One block per b.
// ---------------------------------------------------------------------------
__global__ void k_combine(const float* __restrict__ pm,
                          const float* __restrict__ ps,
                          const float* __restrict__ pr,
                          const float* __restrict__ beta,
                          float* __restrict__ r,
                          float* __restrict__ alpha) {
    const int b   = blockIdx.x;
    const int tid = threadIdx.x;

    __shared__ float wsm[NP];

    // every thread computes M (128 scalar loads, L1-broadcast)
    float M = -INFINITY;
    for (int p = 0; p < NP; ++p) M = fmaxf(M, pm[b * NP + p]);

    // threads 0..NP-1 stash weights
    if (tid < NP) wsm[tid] = expf(pm[b * NP + tid] - M);
    __syncthreads();

    float S = 0.f;
    for (int p = 0; p < NP; ++p) S += wsm[p] * ps[b * NP + p];
    const float invS = 1.f / S;

    // r: weighted combine of partial accumulators (thread owns float4 @ tid)
    float4 acc = make_float4(0.f, 0.f, 0.f, 0.f);
    for (int p = 0; p < NP; ++p) {
        const float wp = wsm[p];
        const float4 v = reinterpret_cast<const float4*>(
            pr + ((size_t)(b * NP + p)) * D)[tid];
        acc.x = fmaf(wp, v.x, acc.x);
        acc.y = fmaf(wp, v.y, acc.y);
        acc.z = fmaf(wp, v.z, acc.z);
        acc.w = fmaf(wp, v.w, acc.w);
    }
    acc.x *= invS; acc.y *= invS; acc.z *= invS; acc.w *= invS;
    reinterpret_cast<float4*>(r + (size_t)b * D)[tid] = acc;

    // alpha
#pragma unroll
    for (int i = 0; i < 8; ++i) {
        const int t = tid + i * 256;
        alpha[b * T + t] = expf(beta[b * T + t] - M) * invS;
    }
}

// ---------------------------------------------------------------------------
extern "C" void kernel_launch(void* const* d_in, const int* in_sizes, int n_in,
                              void* d_out, int out_size, void* d_ws, size_t ws_size,
                              hipStream_t stream) {
    const float* h    = (const float*)d_in[0];   // [B,T,D]
    const float* lstm = (const float*)d_in[1];   // [B,T,D]
    const float* mask = (const float*)d_in[2];   // [B,T,H]

    float* out   = (float*)d_out;
    float* r     = out;            // [B,1,D] -> B*D floats
    float* alpha = out + B * D;    // [B,T]

    float* hsum = (float*)d_ws;                    // B*D          = 32K floats
    float* pm   = hsum + B * D;                    // B*NP         = 4K
    float* ps   = pm + B * NP;                     // B*NP         = 4K
    float* beta = ps + B * NP;                     // B*T          = 64K
    float* pr   = beta + B * T;                    // B*NP*D       = 4M floats

    k_zero   <<<B * D / 1024, 256, 0, stream>>>(hsum);
    k_hsum   <<<B * TS1,      256, 0, stream>>>(h, mask, hsum);
    k_fused  <<<B * NCH,      256, 0, stream>>>(lstm, hsum, beta, pm, ps, pr);
    k_combine<<<B,            256, 0, stream>>>(pm, ps, pr, beta, r, alpha);
}